// Round 19
// baseline (165.373 us; speedup 1.0000x reference)
//
#include <hip/hip_runtime.h>
#include <stdint.h>

typedef uint32_t u32;
typedef unsigned long long u64;
typedef float f4 __attribute__((ext_vector_type(4)));

#define WGATES 32768
#define BATCH  128
#define LAYERS 32
#define NTYPES 16
#define WPL (WGATES * 4)                 // packed words per layer = 131072
#define F4L (WGATES * BATCH / 4)

// ---- ws offsets (u32 units) ----
#define FB_SUB    1024                   // sync: l*1024 + j*16 (j<16)
#define FB_LVL2   34816                  // l*16
#define FB_DONE   35840                  // l*1024 + j*16 (j<64)
#define S_OFF_V8  77824                  // 33-slot packed state
#define WS_NEED_V8  ((size_t)(S_OFF_V8 + 33 * WPL) * 4)   // ~17.6 MB

// sc1 (device-scope) accesses: ONLY for sync + state release. Data reads use
// normal cached loads (each S_l address written once per launch; consumers
// first-touch only after the producer's sc1 store reached the coherence pt).
__device__ __forceinline__ u32 agent_load(const u32* p) {
    return __hip_atomic_load(p, __ATOMIC_RELAXED, __HIP_MEMORY_SCOPE_AGENT);
}
__device__ __forceinline__ void agent_store(u32* p, u32 v) {
    __hip_atomic_store(p, v, __ATOMIC_RELAXED, __HIP_MEMORY_SCOPE_AGENT);
}
__device__ __forceinline__ void agent_store64(u64* p, u64 v) {
    __hip_atomic_store(p, v, __ATOMIC_RELAXED, __HIP_MEMORY_SCOPE_AGENT);
}
__device__ __forceinline__ u32 agent_add(u32* p, u32 v) {
    return __hip_atomic_fetch_add(p, v, __ATOMIC_RELAXED, __HIP_MEMORY_SCOPE_AGENT);
}

__device__ __forceinline__ void lut_masks(u32 tt, u32 m[16]) {
    #pragma unroll
    for (int j = 0; j < 16; ++j)
        m[j] = (u32)(((int)(tt << (31 - j))) >> 31);
}
__device__ __forceinline__ u32 lut_mux(const u32 m[16], u32 a, u32 b, u32 c, u32 d) {
    u32 na = ~a, nb = ~b, nc = ~c, nd = ~d;
    u32 v0 = (m[1]&a)|(m[0]&na),  v1 = (m[3]&a)|(m[2]&na);
    u32 v2 = (m[5]&a)|(m[4]&na),  v3 = (m[7]&a)|(m[6]&na);
    u32 v4 = (m[9]&a)|(m[8]&na),  v5 = (m[11]&a)|(m[10]&na);
    u32 v6 = (m[13]&a)|(m[12]&na),v7 = (m[15]&a)|(m[14]&na);
    u32 u0 = (b&v1)|(nb&v0), u1 = (b&v3)|(nb&v2);
    u32 u2 = (b&v5)|(nb&v4), u3 = (b&v7)|(nb&v6);
    u32 w0 = (c&u1)|(nc&u0), w1 = (c&u3)|(nc&u2);
    return (d&w1)|(nd&w0);
}

__device__ __forceinline__ void unpack_f4(u32 wb, u32 sh, f4* dst) {
    f4 f;
    f.x = ((wb >> (sh    )) & 1) ? 1.0f : 0.0f;
    f.y = ((wb >> (sh + 1)) & 1) ? 1.0f : 0.0f;
    f.z = ((wb >> (sh + 2)) & 1) ? 1.0f : 0.0f;
    f.w = ((wb >> (sh + 3)) & 1) ? 1.0f : 0.0f;
    __builtin_nontemporal_store(f, dst);
}

// Single-lane, single-line poll; compute role slp=1, unpack role slp=8.
__device__ __forceinline__ void fb_wait(const u32* ws, int l, int line,
                                        int tid, int slp) {
    if (tid == 0) {
        const u32* p = ws + FB_DONE + (size_t)l * 1024 + line * 16;
        if (slp == 1) { while (agent_load(p) == 0) __builtin_amdgcn_s_sleep(1); }
        else         { while (agent_load(p) == 0) __builtin_amdgcn_s_sleep(8); }
    }
    __syncthreads();
    asm volatile("" ::: "memory");
}

// ---------------------------------------------------------------------------
// pack_main: tt tables -> ws, zero all sync state, pack h0 -> S_0.
// ---------------------------------------------------------------------------
__global__ void pack_main(const float* __restrict__ feature,
                          const float* __restrict__ activation,
                          u32* __restrict__ ws) {
    int t = blockIdx.x * 256 + threadIdx.x;
    if (blockIdx.x == 0 && threadIdx.x < NTYPES) {
        u32 tt = 0;
        #pragma unroll
        for (int m = 0; m < 16; ++m)
            tt |= (activation[threadIdx.x * 16 + m] != 0.0f ? 1u : 0u) << m;
        ws[threadIdx.x] = tt;
    }
    int z = (int)blockIdx.x - 1;
    if (z >= 0 && z < 288)             // zero [1024, 74752): all sync state
        ws[1024 + z * 256 + threadIdx.x] = 0;
    float v = feature[t];
    u64 m = __ballot(v != 0.0f);
    if ((t & 63) == 0)
        ((u64*)(ws + S_OFF_V8))[t >> 6] = m;
}

// ---------------------------------------------------------------------------
// coop_v8 (proven 165us): persistent producer-consumer.
// Blocks [0,128): compute chain S_1..S_32, gate-per-thread, dwordx4 gathers,
//   16-sub x 8 arrival tree -> lvl2 -> 64-line done broadcast.
// Blocks [128,128+NU): stream-unpack S_0..S_32, XCD-affine slices.
// ---------------------------------------------------------------------------
__global__ __launch_bounds__(256) void coop_v8(
        const int* __restrict__ src_idx,
        const int* __restrict__ cell_type,
        u32* __restrict__ ws,
        float* __restrict__ out,
        int NU)
{
    u32* S = ws + S_OFF_V8;
    int tid = threadIdx.x;
    __shared__ u32 stt[NTYPES];
    if (tid < NTYPES) stt[tid] = ws[tid];
    __syncthreads();

    if ((int)blockIdx.x < 128) {
        // ---------------- compute role: gate-per-thread ----------------
        int g = blockIdx.x * 256 + tid;     // gate id in [0, WGATES)
        int sub = blockIdx.x & 15;          // 16 sub-counters x 8 arrivals
        for (int l = 1; l <= LAYERS; ++l) {
            // Index loads issued BEFORE the gate: latency hides under wait.
            const int4 s = ((const int4*)(src_idx + (size_t)(l - 1) * WGATES * 4))[g];
            u32 ttv = stt[cell_type[(size_t)(l - 1) * WGATES + g]];
            if (l > 1) fb_wait(ws, l - 1, sub, tid, 1);
            const uint4* Sp = (const uint4*)(S + (size_t)(l - 1) * WPL);
            uint4 A = Sp[(u32)s.x], B = Sp[(u32)s.y],
                  C = Sp[(u32)s.z], D = Sp[(u32)s.w];
            u32 m[16];
            lut_masks(ttv, m);
            u32 r0 = lut_mux(m, A.x, B.x, C.x, D.x);
            u32 r1 = lut_mux(m, A.y, B.y, C.y, D.y);
            u32 r2 = lut_mux(m, A.z, B.z, C.z, D.z);
            u32 r3 = lut_mux(m, A.w, B.w, C.w, D.w);
            u64* dst = (u64*)(S + (size_t)l * WPL + (size_t)g * 4);
            agent_store64(dst,     ((u64)r1 << 32) | r0);   // sc1 release
            agent_store64(dst + 1, ((u64)r3 << 32) | r2);
            asm volatile("s_waitcnt vmcnt(0)" ::: "memory");  // stores acked
            __syncthreads();
            if (tid == 0) {
                u32* subp = ws + FB_SUB + (size_t)l * 1024 + sub * 16;
                if (agent_add(subp, 1u) == 7u) {
                    if (agent_add(ws + FB_LVL2 + (size_t)l * 16, 1u) == 15u) {
                        u32* donep = ws + FB_DONE + (size_t)l * 1024;
                        #pragma unroll
                        for (int j = 0; j < 64; ++j)
                            agent_store(donep + j * 16, 1u);
                    }
                }
            }
        }
    } else {
        // ---------------- unpack role ----------------
        int ub = blockIdx.x - 128;
        bool sliced = (NU & 7) == 0;        // XCD-affine slicing
        int x = ub & 7;
        u32 per = (u32)(NU >> 3);
        for (int l = 0; l <= LAYERS; ++l) {
            if (l >= 1) fb_wait(ws, l, ub & 63, tid, 8);
            const u32* Sl = S + (size_t)l * WPL;
            f4* ob = (f4*)(out + (size_t)l * WGATES * BATCH);
            u32 ibeg, iend, istep;
            if (sliced) {
                ibeg = (u32)x * (F4L / 8) + (u32)(ub >> 3) * 256u + tid;
                iend = (u32)x * (F4L / 8) + F4L / 8;
                istep = per * 256u;
            } else {
                ibeg = (u32)ub * 256u + tid; iend = (u32)F4L; istep = (u32)NU * 256u;
            }
            for (u32 i = ibeg; i < iend; i += istep)
                unpack_f4(Sl[i >> 3], (i & 7) * 4, ob + i);
        }
    }
}

// ======================= R2 fallback path (proven) =========================
__global__ void pack_kernel_fb(const float* __restrict__ feature,
                               const float* __restrict__ activation,
                               float* __restrict__ out,
                               u32* __restrict__ tt_ws,
                               u32* __restrict__ buf0) {
    int t = blockIdx.x * 256 + threadIdx.x;
    if (blockIdx.x == 0 && threadIdx.x < NTYPES) {
        u32 tt = 0;
        #pragma unroll
        for (int m = 0; m < 16; ++m)
            tt |= (activation[threadIdx.x * 16 + m] != 0.0f ? 1u : 0u) << m;
        tt_ws[threadIdx.x] = tt;
    }
    float v = feature[t];
    out[t] = v;
    u64 m = __ballot(v != 0.0f);
    if ((t & 63) == 0)
        ((u64*)buf0)[t >> 6] = m;
}

__global__ void fused_kernel_fb(const u32* __restrict__ prev,
                                u32* __restrict__ next,
                                const int* __restrict__ src_idx,
                                const int* __restrict__ cell_type,
                                const u32* __restrict__ tt_ws,
                                const u32* __restrict__ upacked,
                                float* __restrict__ uout,
                                int do_compute)
{
    int tid = threadIdx.x;
    if (do_compute && blockIdx.x < 512) {
        int gl = tid >> 2, q = tid & 3;
        int wg = blockIdx.x * 64 + gl;
        const int4 s = ((const int4*)src_idx)[wg];
        u32 tt = tt_ws[cell_type[wg]];
        u32 m[16];
        lut_masks(tt, m);
        u32 a = prev[(size_t)s.x * 4 + q];
        u32 b = prev[(size_t)s.y * 4 + q];
        u32 c = prev[(size_t)s.z * 4 + q];
        u32 d = prev[(size_t)s.w * 4 + q];
        next[(size_t)wg * 4 + q] = lut_mux(m, a, b, c, d);
        return;
    }
    if (uout == nullptr) return;
    int ub = do_compute ? (int)blockIdx.x - 512 : (int)blockIdx.x;
    #pragma unroll
    for (int r = 0; r < 2; ++r) {
        int fi = ((ub * 2 + r) * 256 + tid) * 4;
        u32 wb = upacked[fi >> 5];
        int sh = fi & 31;
        f4 f;
        f.x = ((wb >> (sh    )) & 1) ? 1.0f : 0.0f;
        f.y = ((wb >> (sh + 1)) & 1) ? 1.0f : 0.0f;
        f.z = ((wb >> (sh + 2)) & 1) ? 1.0f : 0.0f;
        f.w = ((wb >> (sh + 3)) & 1) ? 1.0f : 0.0f;
        ((f4*)uout)[fi >> 2] = f;
    }
}

static void launch_fallback(const float* feature, const float* activation,
                            const int* src_idx, const int* cell_type,
                            float* out, void* d_ws, hipStream_t stream) {
    u32* tt_ws = (u32*)d_ws;
    u32* bufA = (u32*)((char*)d_ws + 1024);
    u32* bufB = (u32*)((char*)d_ws + 1024 + WGATES * 16);
    pack_kernel_fb<<<WGATES * BATCH / 256, 256, 0, stream>>>(
        feature, activation, out, tt_ws, bufA);
    for (int l = 1; l <= LAYERS; ++l) {
        u32* prev = ((l - 1) & 1) ? bufB : bufA;
        u32* next = ((l - 1) & 1) ? bufA : bufB;
        float* uout = (l >= 2) ? out + (size_t)(l - 1) * WGATES * BATCH : nullptr;
        fused_kernel_fb<<<512 + 2048, 256, 0, stream>>>(
            prev, next,
            src_idx + (size_t)(l - 1) * WGATES * 4,
            cell_type + (size_t)(l - 1) * WGATES,
            tt_ws, prev, uout, 1);
    }
    u32* s32 = ((LAYERS - 1) & 1) ? bufA : bufB;
    fused_kernel_fb<<<2048, 256, 0, stream>>>(
        s32, s32, src_idx, cell_type, tt_ws,
        s32, out + (size_t)LAYERS * WGATES * BATCH, 0);
}

extern "C" void kernel_launch(void* const* d_in, const int* in_sizes, int n_in,
                              void* d_out, int out_size, void* d_ws, size_t ws_size,
                              hipStream_t stream) {
    const float* feature    = (const float*)d_in[0];
    const float* activation = (const float*)d_in[1];
    const int*   src_idx    = (const int*)d_in[2];
    const int*   cell_type  = (const int*)d_in[3];
    float* out = (float*)d_out;
    u32* ws = (u32*)d_ws;

    int dev = 0, numCU = 0;
    (void)hipGetDevice(&dev);
    bool have_dev = hipDeviceGetAttribute(
        &numCU, hipDeviceAttributeMultiprocessorCount, dev) == hipSuccess;

    if (have_dev && ws_size >= WS_NEED_V8) {
        int bpc = 0;
        if (hipOccupancyMaxActiveBlocksPerMultiprocessor(
                &bpc, (const void*)coop_v8, 256, 0) == hipSuccess) {
            int G = bpc * numCU;
            if (G > 2048) G = 2048;
            int NU = G - 128;
            if (NU >= 256) {
                pack_main<<<WGATES * BATCH / 256, 256, 0, stream>>>(
                    feature, activation, ws);
                void* args[] = {(void*)&src_idx, (void*)&cell_type,
                                (void*)&ws, (void*)&out, (void*)&NU};
                if (hipLaunchCooperativeKernel((const void*)coop_v8,
                        dim3(G), dim3(256), args, 0, stream) == hipSuccess)
                    return;
            }
        }
    }
    launch_fallback(feature, activation, src_idx, cell_type, out, d_ws, stream);
}